// Round 25
// baseline (51.888 us; speedup 1.0000x reference)
//
#include <hip/hip_runtime.h>
#include <hip/hip_fp16.h>

#define W 256
#define NA 180
#define STRIDE 89             // words per window row; compile-time, odd -> bank spread
#define NROWS_A 169           // worst-case rows; 169*89 = 15,041 words
#define SALLOC 15056          // 60,224 B -> 2 blocks/CU, 32 waves/CU

// Block = (angle a, batch n, column-quarter cq): 64 columns x full r-range.
// Fixed-stride window of the tap bbox (biased: half = px+2, row = py+1).

__global__ __launch_bounds__(1024, 8) void radon_kernel(
    const float* __restrict__ x, const int* __restrict__ index_p,
    float* __restrict__ out)
{
    __shared__ unsigned sw[SALLOC];

    const int a = blockIdx.x;
    const int n = blockIdx.y;
    const int cq = blockIdx.z;       // 0..3
    const int tid = threadIdx.x;
    const int cl = tid & 63;         // lane = local column
    const int s = tid >> 6;          // r-chunk / stage row group, 0..15 (wave-uniform)

    const int index = *index_p;
    const int seg[6] = {1, 26, 51, 77, 102, 128};
    const int t0 = seg[4 - index];
    const int t1 = seg[4 - index + 1];
    const int r1lo = 128 - t1;
    const int r0lo = 128 - t0, r0hi = 127 + t0;
    const int total = 2 * t1;

    float sa, ca;
    sincosf((float)a * 0.017453292519943295f, &sa, &ca);

    // ---- window bbox from the 4 (xc, rf) corners (block-uniform; R22-verified) ----
    const float xcl = ((2.0f * (float)(cq * 64) + 1.0f) * (1.0f / 256.0f)) - 1.0f;
    const float xch = ((2.0f * (float)(cq * 64 + 63) + 1.0f) * (1.0f / 256.0f)) - 1.0f;
    const float rflo = (float)r1lo - 127.5f;
    const float rfhi = rflo + (float)(total - 1);
    const float bxl = fmaf(128.0f * ca, xcl, 129.5f);
    const float bxh = fmaf(128.0f * ca, xch, 129.5f);
    const float byl = fmaf(-128.0f * sa, xcl, 128.5f);
    const float byh = fmaf(-128.0f * sa, xch, 128.5f);

    float ixmin = fminf(fminf(fmaf(sa, rflo, bxl), fmaf(sa, rfhi, bxl)),
                        fminf(fmaf(sa, rflo, bxh), fmaf(sa, rfhi, bxh)));
    float ixmax = fmaxf(fmaxf(fmaf(sa, rflo, bxl), fmaf(sa, rfhi, bxl)),
                        fmaxf(fmaf(sa, rflo, bxh), fmaf(sa, rfhi, bxh)));
    float iymin = fminf(fminf(fmaf(ca, rflo, byl), fmaf(ca, rfhi, byl)),
                        fminf(fmaf(ca, rflo, byh), fmaf(ca, rfhi, byh)));
    float iymax = fmaxf(fmaxf(fmaf(ca, rflo, byl), fmaf(ca, rfhi, byl)),
                        fmaxf(fmaf(ca, rflo, byh), fmaf(ca, rfhi, byh)));
    ixmin = __builtin_amdgcn_fmed3f(ixmin, 1.0f, 258.0f);
    ixmax = __builtin_amdgcn_fmed3f(ixmax, 1.0f, 258.0f);
    iymin = __builtin_amdgcn_fmed3f(iymin, 0.0f, 257.0f);
    iymax = __builtin_amdgcn_fmed3f(iymax, 0.0f, 257.0f);

    const int gx0 = ((int)ixmin) & ~1;            // even
    const int gx1 = (int)ixmax + 1;
    const int gy0 = (int)iymin;
    const int gy1 = (int)iymax + 1;
    const int nw = ((gx1 >> 1) - (gx0 >> 1)) + 2; // <= 86 for index=2
    const int nrows = min(gy1 - gy0 + 1, NROWS_A);

    const int pylo = max(gy0 - 1, 0);
    const int pyhi = min(gy1 - 1, 255);
    const int nlr = pyhi - pylo + 1;
    const int lbase = pylo + 1 - gy0;             // 0 or 1
    const int pxlo = max(gx0 - 2, 0);             // even
    const int pxhi = min(gx1 - 2, 255);
    const int wv0 = (pxlo - gx0 + 2) >> 1;        // 0 or 1
    const int nq2 = min((pxhi - pxlo + 2) >> 1, STRIDE - wv0);

    // ---- guard superset zero: rows {0,1,nrows-2,nrows-1} full, cols {0,1,nw-2,nw-1} ----
    for (int i = tid; i < 356 + 4 * nrows; i += 1024) {
        if (i < 356) {                           // 4 rows x 89 words
            const int rr = i / 89;               // const div -> magic mul
            const int w = i - rr * 89;
            const int row = (rr < 2) ? rr : (nrows - 4 + rr);
            sw[row * STRIDE + w] = 0u;
        } else {
            const int i2 = i - 356;
            const int row = i2 >> 2;
            const int ww = i2 & 3;
            const int w = (ww < 2) ? ww : (nw - 4 + ww);
            sw[row * STRIDE + w] = 0u;
        }
    }
    __syncthreads();                             // zeros land before staging overwrites

    // ---- stage valid sub-rectangle (lane-uniform 2D loop, float2/even px) ----
    {
        const float* __restrict__ img = x + (size_t)n * W * W;
        for (int lr = s; lr < nlr; lr += 16) {
            const int wb = (lbase + lr) * STRIDE + wv0;
            const float* rowp = img + (pylo + lr) * W + pxlo;
            for (int q = cl; q < nq2; q += 64) {
                const float2 v = *(const float2*)(rowp + 2 * q);
                const __half2 hp = __floats2half2_rn(v.x, v.y);
                sw[wb + q] = *(const unsigned*)&hp;
            }
        }
    }
    __syncthreads();

    // ---- tap loop (R19 body; compile-time stride, window-local base) ----
    const int c = cq * 64 + cl;
    const float xc = ((2.0f * (float)c + 1.0f) * (1.0f / 256.0f)) - 1.0f;
    const float bx = fmaf(128.0f * ca, xc, 129.5f);
    const float by = fmaf(-128.0f * sa, xc, 128.5f);
    const int wbase = -(gy0 * STRIDE + (gx0 >> 1));

    const int chunk = (total + 15) >> 4;
    const int rs = r1lo + s * chunk;
    const int re = min(rs + chunk, r1lo + total);

#define TAP_BODY                                                              \
        float ix = fmaf(sa, rf, bx);                                          \
        float iy = fmaf(ca, rf, by);                                          \
        ix = __builtin_amdgcn_fmed3f(ix, 1.0f, 258.0f);                       \
        iy = __builtin_amdgcn_fmed3f(iy, 0.0f, 257.0f);                       \
        const float wx = __builtin_amdgcn_fractf(ix);                         \
        const float wy = __builtin_amdgcn_fractf(iy);                         \
        const int x0 = (int)ix;                                               \
        const int y0 = (int)iy;                                               \
        const int wi = y0 * STRIDE + (x0 >> 1) + wbase;                       \
        const unsigned A0 = sw[wi];                                           \
        const unsigned B0 = sw[wi + 1];                                       \
        const unsigned A1 = sw[wi + STRIDE];                                  \
        const unsigned B1 = sw[wi + STRIDE + 1];                              \
        const int sh = (x0 & 1) << 4;                                         \
        const unsigned q0 = __builtin_amdgcn_alignbit(B0, A0, sh);            \
        const unsigned q1 = __builtin_amdgcn_alignbit(B1, A1, sh);            \
        const __half2 h0 = *(const __half2*)&q0;                              \
        const __half2 h1 = *(const __half2*)&q1;                              \
        const __half2 wy2 = __float2half2_rn(wy);                             \
        const __half2 t = __hfma2(wy2, __hsub2(h1, h0), h0);                  \
        const float tl = __low2float(t);                                      \
        const float th = __high2float(t);                                     \
        const float val = fmaf(wx, th - tl, tl);

    float sumA = 0.0f, sumB = 0.0f, sumC = 0.0f;
    {   // segment A: outer mask only
        const int e = min(re, r0lo);
        float rf = (float)rs - 127.5f;
        #pragma unroll 4
        for (int r = rs; r < e; ++r, rf += 1.0f) { TAP_BODY sumA += val; }
    }
    {   // segment B: both masks
        const int b = max(rs, r0lo);
        const int e = min(re, r0hi + 1);
        float rf = (float)b - 127.5f;
        #pragma unroll 4
        for (int r = b; r < e; ++r, rf += 1.0f) { TAP_BODY sumB += val; }
    }
    {   // segment C: outer mask only
        const int b = max(rs, r0hi + 1);
        float rf = (float)b - 127.5f;
        #pragma unroll 4
        for (int r = b; r < re; ++r, rf += 1.0f) { TAP_BODY sumC += val; }
    }
#undef TAP_BODY

    const float sum0 = sumB;
    const float sum1 = sumA + sumB + sumC;

    // ---- reduce 16 partials; reuse sw as scratch ----
    __syncthreads();
    float* red = (float*)sw;                 // 8 KB of 60 KB
    red[(0 * 16 + s) * 64 + cl] = sum0;
    red[(1 * 16 + s) * 64 + cl] = sum1;
    __syncthreads();

    if (s == 0) {
        float a0 = 0.0f, a1 = 0.0f;
        #pragma unroll
        for (int j = 0; j < 16; ++j) {
            a0 += red[(0 * 16 + j) * 64 + cl];
            a1 += red[(1 * 16 + j) * 64 + cl];
        }
        out[(((size_t)n * 2 + 0) * W + c) * NA + a] = a0 * (1.0f / (float)(2 * t0));
        out[(((size_t)n * 2 + 1) * W + c) * NA + a] = a1 * (1.0f / (float)(2 * t1));
    }
}

extern "C" void kernel_launch(void* const* d_in, const int* in_sizes, int n_in,
                              void* d_out, int out_size, void* d_ws, size_t ws_size,
                              hipStream_t stream) {
    const float* x = (const float*)d_in[0];
    const int* index_p = (const int*)d_in[1];
    float* out = (float*)d_out;
    const int N = in_sizes[0] / (W * W); // 4
    dim3 grid(NA, N, 4);                 // 4 column-quarters x full r
    radon_kernel<<<grid, 1024, 0, stream>>>(x, index_p, out);
}